// Round 10
// baseline (140.659 us; speedup 1.0000x reference)
//
#include <hip/hip_runtime.h>

#define NB    256
#define UNITS 1024
#define EDIM  1024
#define MEM   128
#define LDA   2048   // inputs row stride (EDIM + UNITS)

// d_out layout (floats): output[256*1024] | new_M_key[256*128*1024] | new_M_value[256*128*1024]
#define KEY_OFF ((size_t)NB * UNITS)
#define VAL_OFF (KEY_OFF + (size_t)NB * MEM * UNITS)

#define NGEMM 128                 // GEMM blocks (last in grid)
#define GROUP_F 4224              // GEMM: floats per split-K group region (As 32x68 + Bs 32x64)

// fused-path LDS: buf[2][8192] (2x32KB tiles) | h 1024 | lg2 256 | at 128
#define BUF0    0
#define H_OFF   16384
#define LG2_OFF 17408
#define AT_OFF  17664
#define SMEM_FLOATS 17792         // 71168 B (>= GEMM's 4*GROUP_F = 16896 floats)

// async global->LDS DMA: 16B per lane, wave-uniform LDS base + lane*16
__device__ __forceinline__ void dma16(const float* g, float* l) {
    __builtin_amdgcn_global_load_lds((const __attribute__((address_space(1))) void*)g,
                                     (__attribute__((address_space(3))) void*)l, 16, 0, 0);
}

// counted vmcnt wait: allow N newest VMEM ops outstanding; in-order retire
// guarantees everything older is complete (m135 semantics).
#define WAITV2() do { asm volatile("s_waitcnt vmcnt(2)" ::: "memory"); \
                      __builtin_amdgcn_sched_barrier(0); } while (0)

// Blocks 0..255: fused attention + shift. Per-wave PRIVATE pipeline: wave w
//   stages AND consumes the same half-row region [w*512, w*512+512) of each
//   32KB tile (r=w>>1, hh=w&1) -> zero cross-wave LDS deps -> NO in-loop
//   barriers. Counted s_waitcnt vmcnt(2) keeps the next tile's DMA in flight
//   across iterations (true depth-1 pipeline, never re-drained).
// Blocks 256..383: two 256x1024x1024 fp32 GEMMs (row 127 of new_M_*),
//   LDS-staged, in-block split-K=4 (R4 structure, proven).
__global__ __launch_bounds__(1024, 8) void k_all(
    const float* __restrict__ inputs, const float* __restrict__ M_key,
    const float* __restrict__ M_value, const float* __restrict__ W_key,
    const float* __restrict__ W_value, float* __restrict__ out)
{
    __shared__ __align__(16) float smem[SMEM_FLOATS];
    const int tid = threadIdx.x;

    if (blockIdx.x < NB) {
        // ========================= fused path =========================
        const int b    = blockIdx.x;
        const int wave = tid >> 6;
        const int lane = tid & 63;
        const int r    = wave >> 1;    // row within tile this wave owns
        const int hh   = wave & 1;     // column half this wave owns
        const int reg  = wave * 512;   // this wave's region inside a tile buffer

        const size_t mb = (size_t)b * (MEM * UNITS);
        const float* kbase = M_key   + mb;
        const float* vbase = M_value + mb;
        float*       kout  = out + KEY_OFF + mb;
        float*       vout  = out + VAL_OFF + mb;

        smem[H_OFF + tid] = inputs[(size_t)b * LDA + EDIM + tid];

        // prologue: stage K tile 0 into slot 0 (drained by the next barrier)
        dma16(kbase + reg + lane * 4,       smem + BUF0 + reg);
        dma16(kbase + reg + 256 + lane * 4, smem + BUF0 + reg + 256);
        __syncthreads();   // h ready + K tile 0 landed (vmcnt(0) implied)

        const float4 h0 = *(const float4*)(&smem[H_OFF + hh * 512 + lane * 4]);
        const float4 h1 = *(const float4*)(&smem[H_OFF + hh * 512 + lane * 4 + 256]);

        // ---- Phase A: K-pass, 16 tiles of 8 rows, barrier-free ----
        for (int t = 0; t < 15; ++t) {
            const float* src = kbase + (size_t)(t + 1) * 8192;
            float* lb = smem + ((t + 1) & 1) * 8192;
            dma16(src + reg + lane * 4,       lb + reg);
            dma16(src + reg + 256 + lane * 4, lb + reg + 256);
            WAITV2();   // tile t's DMA (and older stores) retired; D(t+1) flies
            {
                const float* lbc = smem + (t & 1) * 8192 + reg;
                float4 x0 = *(const float4*)(lbc + lane * 4);
                float4 x1 = *(const float4*)(lbc + 256 + lane * 4);

                float a = x0.x*h0.x + x0.y*h0.y + x0.z*h0.z + x0.w*h0.w
                        + x1.x*h1.x + x1.y*h1.y + x1.z*h1.z + x1.w*h1.w;
                #pragma unroll
                for (int off = 32; off > 0; off >>= 1)
                    a += __shfl_xor(a, off);
                const int m = t * 8 + r;
                if (lane == 0) smem[LG2_OFF + m * 2 + hh] = a;

                if (m > 0) {
                    float* dst = kout + (size_t)(m - 1) * 1024 + hh * 512 + lane * 4;
                    *(float4*)(dst)       = x0;
                    *(float4*)(dst + 256) = x1;
                }
            }
        }
        // epilogue tile 15
        WAITV2();
        {
            const float* lbc = smem + (15 & 1) * 8192 + reg;
            float4 x0 = *(const float4*)(lbc + lane * 4);
            float4 x1 = *(const float4*)(lbc + 256 + lane * 4);
            float a = x0.x*h0.x + x0.y*h0.y + x0.z*h0.z + x0.w*h0.w
                    + x1.x*h1.x + x1.y*h1.y + x1.z*h1.z + x1.w*h1.w;
            #pragma unroll
            for (int off = 32; off > 0; off >>= 1)
                a += __shfl_xor(a, off);
            const int m = 120 + r;
            if (lane == 0) smem[LG2_OFF + m * 2 + hh] = a;
            float* dst = kout + (size_t)(m - 1) * 1024 + hh * 512 + lane * 4;
            *(float4*)(dst)       = x0;
            *(float4*)(dst + 256) = x1;
        }
        __syncthreads();   // lg2 visible to wave 0

        // ---- softmax over 128 logits (wave 0); all waves stage V tile 0 ----
        if (wave == 0) {
            float l0 = smem[LG2_OFF + lane * 2]        + smem[LG2_OFF + lane * 2 + 1];
            float l1 = smem[LG2_OFF + (lane + 64) * 2] + smem[LG2_OFF + (lane + 64) * 2 + 1];
            float mx = fmaxf(l0, l1);
            #pragma unroll
            for (int off = 32; off > 0; off >>= 1)
                mx = fmaxf(mx, __shfl_xor(mx, off));
            float e0 = __expf(l0 - mx), e1 = __expf(l1 - mx);
            float s = e0 + e1;
            #pragma unroll
            for (int off = 32; off > 0; off >>= 1)
                s += __shfl_xor(s, off);
            float inv = 1.0f / s;
            smem[AT_OFF + lane]      = e0 * inv;
            smem[AT_OFF + lane + 64] = e1 * inv;
        }
        dma16(vbase + reg + lane * 4,       smem + BUF0 + reg);
        dma16(vbase + reg + 256 + lane * 4, smem + BUF0 + reg + 256);
        __syncthreads();   // at ready + V tile 0 landed

        // ---- Phase C: V-pass, 16 tiles of 8 rows, barrier-free ----
        float4 acc0 = {0.f, 0.f, 0.f, 0.f};
        float4 acc1 = {0.f, 0.f, 0.f, 0.f};
        for (int t = 0; t < 15; ++t) {
            const float* src = vbase + (size_t)(t + 1) * 8192;
            float* lb = smem + ((t + 1) & 1) * 8192;
            dma16(src + reg + lane * 4,       lb + reg);
            dma16(src + reg + 256 + lane * 4, lb + reg + 256);
            WAITV2();
            {
                const float* lbc = smem + (t & 1) * 8192 + reg;
                float4 x0 = *(const float4*)(lbc + lane * 4);
                float4 x1 = *(const float4*)(lbc + 256 + lane * 4);

                const int m = t * 8 + r;
                const float w = smem[AT_OFF + m];
                acc0.x = fmaf(w, x0.x, acc0.x); acc0.y = fmaf(w, x0.y, acc0.y);
                acc0.z = fmaf(w, x0.z, acc0.z); acc0.w = fmaf(w, x0.w, acc0.w);
                acc1.x = fmaf(w, x1.x, acc1.x); acc1.y = fmaf(w, x1.y, acc1.y);
                acc1.z = fmaf(w, x1.z, acc1.z); acc1.w = fmaf(w, x1.w, acc1.w);

                if (m > 0) {
                    float* dst = vout + (size_t)(m - 1) * 1024 + hh * 512 + lane * 4;
                    *(float4*)(dst)       = x0;
                    *(float4*)(dst + 256) = x1;
                }
            }
        }
        WAITV2();
        {
            const float* lbc = smem + (15 & 1) * 8192 + reg;
            float4 x0 = *(const float4*)(lbc + lane * 4);
            float4 x1 = *(const float4*)(lbc + 256 + lane * 4);
            const int m = 120 + r;
            const float w = smem[AT_OFF + m];
            acc0.x = fmaf(w, x0.x, acc0.x); acc0.y = fmaf(w, x0.y, acc0.y);
            acc0.z = fmaf(w, x0.z, acc0.z); acc0.w = fmaf(w, x0.w, acc0.w);
            acc1.x = fmaf(w, x1.x, acc1.x); acc1.y = fmaf(w, x1.y, acc1.y);
            acc1.z = fmaf(w, x1.z, acc1.z); acc1.w = fmaf(w, x1.w, acc1.w);
            float* dst = vout + (size_t)(m - 1) * 1024 + hh * 512 + lane * 4;
            *(float4*)(dst)       = x0;
            *(float4*)(dst + 256) = x1;
        }

        // per-wave output partials -> slot 0 region (wave-private, safe skewed)
        *(float4*)(&smem[reg + lane * 4])       = acc0;
        *(float4*)(&smem[reg + 256 + lane * 4]) = acc1;
        __syncthreads();

        // combine 8 wave-partials per column half
        {
            const int half = tid >> 9;
            const int idx  = tid & 511;
            float s = 0.f;
            #pragma unroll
            for (int j = 0; j < 8; ++j)
                s += smem[(2 * j + half) * 512 + idx];
            out[(size_t)b * UNITS + tid] = s;
        }
    } else {
        // ========================= GEMM path (R4 structure) =========================
        const int t  = blockIdx.x - NB;       // 0..127
        const int w  = t >> 6;                // which W matrix
        const int rr = t & 63;
        const int mt = rr >> 4;               // 0..3  (64 rows)
        const int nt = rr & 15;               // 0..15 (64 cols)
        const int kc   = tid >> 8;            // 0..3 (split-K group)
        const int gtid = tid & 255;
        const int ty = gtid >> 4, tx = gtid & 15;

        float* region = smem + kc * GROUP_F;
        float (*As)[68] = (float (*)[68])region;            // [k][m]
        float (*Bs)[64] = (float (*)[64])(region + 2176);   // [k][n]
        const float* Wm = w ? W_value : W_key;

        float acc[4][4] = {};
        const int k0 = kc * 256;

        for (int kt = k0; kt < k0 + 256; kt += 32) {
            #pragma unroll
            for (int q = 0; q < 2; ++q) {
                const int f  = gtid * 2 + q;          // 0..511
                const int ar = f >> 3;                // 0..63
                const int ac = (f & 7) << 2;          // 0..28
                float4 a = *(const float4*)(inputs + (size_t)(mt * 64 + ar) * LDA + kt + ac);
                As[ac + 0][ar] = a.x;
                As[ac + 1][ar] = a.y;
                As[ac + 2][ar] = a.z;
                As[ac + 3][ar] = a.w;
            }
            #pragma unroll
            for (int q = 0; q < 2; ++q) {
                const int f  = gtid * 2 + q;
                const int br = f >> 4;                // 0..31
                const int bc = (f & 15) << 2;         // 0..60
                *(float4*)(&Bs[br][bc]) =
                    *(const float4*)(Wm + (size_t)(kt + br) * UNITS + nt * 64 + bc);
            }
            __syncthreads();

            #pragma unroll
            for (int kk = 0; kk < 32; ++kk) {
                const float4 av = *(const float4*)(&As[kk][ty * 4]);
                const float4 bv = *(const float4*)(&Bs[kk][tx * 4]);
                acc[0][0] += av.x * bv.x; acc[0][1] += av.x * bv.y; acc[0][2] += av.x * bv.z; acc[0][3] += av.x * bv.w;
                acc[1][0] += av.y * bv.x; acc[1][1] += av.y * bv.y; acc[1][2] += av.y * bv.z; acc[1][3] += av.y * bv.w;
                acc[2][0] += av.z * bv.x; acc[2][1] += av.z * bv.y; acc[2][2] += av.z * bv.z; acc[2][3] += av.z * bv.w;
                acc[3][0] += av.w * bv.x; acc[3][1] += av.w * bv.y; acc[3][2] += av.w * bv.z; acc[3][3] += av.w * bv.w;
            }
            __syncthreads();
        }

        // each group writes its 64x64 partial over its own As/Bs region
        #pragma unroll
        for (int i = 0; i < 4; ++i) {
            float4 v = {acc[i][0], acc[i][1], acc[i][2], acc[i][3]};
            *(float4*)(region + (ty * 4 + i) * 64 + tx * 4) = v;
        }
        __syncthreads();

        // block-wide reduce of the 4 partials -> row 127 of new_M_{key,value}
        {
            const int e   = tid * 4;                  // 0..4092
            const int row = e >> 6;                   // 0..63
            const int col = e & 63;
            float4 p0 = *(const float4*)(smem + 0 * GROUP_F + e);
            float4 p1 = *(const float4*)(smem + 1 * GROUP_F + e);
            float4 p2 = *(const float4*)(smem + 2 * GROUP_F + e);
            float4 p3 = *(const float4*)(smem + 3 * GROUP_F + e);
            float4 s = {p0.x + p1.x + p2.x + p3.x,
                        p0.y + p1.y + p2.y + p3.y,
                        p0.z + p1.z + p2.z + p3.z,
                        p0.w + p1.w + p2.w + p3.w};
            *(float4*)(out + (w ? VAL_OFF : KEY_OFF)
                       + (size_t)(mt * 64 + row) * (MEM * UNITS)
                       + (size_t)(MEM - 1) * UNITS + nt * 64 + col) = s;
        }
    }
}

extern "C" void kernel_launch(void* const* d_in, const int* in_sizes, int n_in,
                              void* d_out, int out_size, void* d_ws, size_t ws_size,
                              hipStream_t stream)
{
    const float* inputs  = (const float*)d_in[0];
    const float* M_key   = (const float*)d_in[1];
    const float* M_value = (const float*)d_in[2];
    const float* W_key   = (const float*)d_in[3];
    const float* W_value = (const float*)d_in[4];
    float* out = (float*)d_out;

    hipLaunchKernelGGL(k_all, dim3(NB + NGEMM), dim3(1024), 0, stream,
                       inputs, M_key, M_value, W_key, W_value, out);
}

// Round 11
// 117.751 us; speedup vs baseline: 1.1945x; 1.1945x over previous
//
#include <hip/hip_runtime.h>

#define NB    256
#define UNITS 1024
#define EDIM  1024
#define MEM   128
#define LDA   2048   // inputs row stride (EDIM + UNITS)

// d_out layout (floats): output[256*1024] | new_M_key[256*128*1024] | new_M_value[256*128*1024]
#define KEY_OFF ((size_t)NB * UNITS)
#define VAL_OFF (KEY_OFF + (size_t)NB * MEM * UNITS)

#define NGEMM 128                 // GEMM blocks (last in grid)
#define GROUP_F 4224              // GEMM: floats per split-K group region (As 32x68 + Bs 32x64)

#define NT 32                     // 32 tiles x 4 rows = 128 rows per stream
// fused LDS (floats): Kbuf[2][4096] | Vbuf[2][4096] | h[1024] | lg2[256] | zp[16]
#define KBUF    0
#define VBUF    8192
#define H_OFF   16384
#define LG2_OFF 17408
#define ZP_OFF  17664
#define SMEM_FLOATS 17680         // 70720 B (> GEMM's 4*GROUP_F = 16896 floats)

// async global->LDS DMA: 16B per lane, wave-uniform LDS base + lane*16
__device__ __forceinline__ void dma16(const float* g, float* l) {
    __builtin_amdgcn_global_load_lds((const __attribute__((address_space(1))) void*)g,
                                     (__attribute__((address_space(3))) void*)l, 16, 0, 0);
}

// Blocks 0..255: fused attention + shift, SINGLE merged streaming pass.
//   Waves 0-7 (K-group): stage+consume K tiles: dot partials -> lg2, copy rows.
//   Waves 8-15 (V-group): stage V tiles; consume one tile BEHIND: p=exp(l-8)
//   from lg2 (published by last barrier), o += p*v, Z += p, copy rows.
//   Online softmax (shift-invariant, exact). One barrier per 4-row tile;
//   V never re-read. R9's DMA machinery throughout.
// Blocks 256..383: two 256x1024x1024 fp32 GEMMs (row 127 of new_M_*),
//   LDS-staged, in-block split-K=4 (R4 structure, proven).
__global__ __launch_bounds__(1024, 8) void k_all(
    const float* __restrict__ inputs, const float* __restrict__ M_key,
    const float* __restrict__ M_value, const float* __restrict__ W_key,
    const float* __restrict__ W_value, float* __restrict__ out)
{
    __shared__ __align__(16) float smem[SMEM_FLOATS];
    const int tid = threadIdx.x;

    if (blockIdx.x < NB) {
        // ========================= fused path =========================
        const int b    = blockIdx.x;
        const int wave = tid >> 6;
        const int lane = tid & 63;
        const bool isK = wave < 8;
        const int vw   = wave & 7;      // slot within group
        const int rr   = vw >> 1;       // row within 4-row tile
        const int hh   = vw & 1;        // column half
        const int reg  = vw * 512;      // region within a tile buffer

        const size_t mb = (size_t)b * (MEM * UNITS);
        const float* kbase = M_key   + mb;
        const float* vbase = M_value + mb;
        float*       kout  = out + KEY_OFF + mb;
        float*       vout  = out + VAL_OFF + mb;

        smem[H_OFF + tid] = inputs[(size_t)b * LDA + EDIM + tid];

        // prologue: K-group stages K tile 0
        if (isK) {
            dma16(kbase + reg + lane * 4,       smem + KBUF + reg);
            dma16(kbase + reg + 256 + lane * 4, smem + KBUF + reg + 256);
        }
        __syncthreads();   // h ready + K(0) landed

        float4 h0 = {0.f,0.f,0.f,0.f}, h1 = {0.f,0.f,0.f,0.f};
        if (isK) {
            h0 = *(const float4*)(&smem[H_OFF + hh * 512 + lane * 4]);
            h1 = *(const float4*)(&smem[H_OFF + hh * 512 + lane * 4 + 256]);
        }
        float4 acc0 = {0.f,0.f,0.f,0.f}, acc1 = {0.f,0.f,0.f,0.f};
        float  Zp = 0.f;

        for (int t = 0; t <= NT; ++t) {
            if (isK) {
                if (t + 1 < NT) {   // stage K(t+1)
                    const float* src = kbase + (size_t)(t + 1) * 4096;
                    float* lb = smem + KBUF + ((t + 1) & 1) * 4096;
                    dma16(src + reg + lane * 4,       lb + reg);
                    dma16(src + reg + 256 + lane * 4, lb + reg + 256);
                }
                if (t < NT) {       // consume K(t)
                    const float* lb = smem + KBUF + (t & 1) * 4096 + reg;
                    float4 x0 = *(const float4*)(lb + lane * 4);
                    float4 x1 = *(const float4*)(lb + 256 + lane * 4);

                    float a = x0.x*h0.x + x0.y*h0.y + x0.z*h0.z + x0.w*h0.w
                            + x1.x*h1.x + x1.y*h1.y + x1.z*h1.z + x1.w*h1.w;
                    #pragma unroll
                    for (int off = 32; off > 0; off >>= 1)
                        a += __shfl_xor(a, off);
                    const int m = t * 4 + rr;
                    if (lane == 0) smem[LG2_OFF + m * 2 + hh] = a;

                    if (m > 0) {
                        float* dst = kout + (size_t)(m - 1) * 1024 + hh * 512 + lane * 4;
                        *(float4*)(dst)       = x0;
                        *(float4*)(dst + 256) = x1;
                    }
                }
            } else {
                if (t < NT) {       // stage V(t)
                    const float* src = vbase + (size_t)t * 4096;
                    float* lb = smem + VBUF + (t & 1) * 4096;
                    dma16(src + reg + lane * 4,       lb + reg);
                    dma16(src + reg + 256 + lane * 4, lb + reg + 256);
                }
                if (t >= 1) {       // consume V(t-1), weights from lg2 (last iter)
                    const int tv = t - 1;
                    const float* lb = smem + VBUF + (tv & 1) * 4096 + reg;
                    float4 x0 = *(const float4*)(lb + lane * 4);
                    float4 x1 = *(const float4*)(lb + 256 + lane * 4);

                    const int m = tv * 4 + rr;
                    const float l = smem[LG2_OFF + m * 2] + smem[LG2_OFF + m * 2 + 1];
                    const float p = __expf(l - 8.0f);   // shift-invariant; |l| << 80
                    Zp += p;
                    acc0.x = fmaf(p, x0.x, acc0.x); acc0.y = fmaf(p, x0.y, acc0.y);
                    acc0.z = fmaf(p, x0.z, acc0.z); acc0.w = fmaf(p, x0.w, acc0.w);
                    acc1.x = fmaf(p, x1.x, acc1.x); acc1.y = fmaf(p, x1.y, acc1.y);
                    acc1.z = fmaf(p, x1.z, acc1.z); acc1.w = fmaf(p, x1.w, acc1.w);

                    if (m > 0) {
                        float* dst = vout + (size_t)(m - 1) * 1024 + hh * 512 + lane * 4;
                        *(float4*)(dst)       = x0;
                        *(float4*)(dst + 256) = x1;
                    }
                }
            }
            __syncthreads();   // publish lg2(t); drain K(t+1) & V(t) DMA
        }

        // epilogue: V-group publishes o/Z partials (Kbuf is dead)
        if (!isK) {
            *(float4*)(&smem[KBUF + reg + lane * 4])       = acc0;
            *(float4*)(&smem[KBUF + reg + 256 + lane * 4]) = acc1;
            if (lane == 0) smem[ZP_OFF + vw] = Zp;
        }
        __syncthreads();

        {
            const int half = tid >> 9;
            const int idx  = tid & 511;
            const float Z = smem[ZP_OFF + 0] + smem[ZP_OFF + 2]
                          + smem[ZP_OFF + 4] + smem[ZP_OFF + 6];
            float s = smem[KBUF + (0 + half) * 512 + idx]
                    + smem[KBUF + (2 + half) * 512 + idx]
                    + smem[KBUF + (4 + half) * 512 + idx]
                    + smem[KBUF + (6 + half) * 512 + idx];
            out[(size_t)b * UNITS + tid] = s / Z;
        }
    } else {
        // ========================= GEMM path (R4 structure) =========================
        const int t  = blockIdx.x - NB;       // 0..127
        const int w  = t >> 6;                // which W matrix
        const int rg = t & 63;
        const int mt = rg >> 4;               // 0..3  (64 rows)
        const int nt = rg & 15;               // 0..15 (64 cols)
        const int kc   = tid >> 8;            // 0..3 (split-K group)
        const int gtid = tid & 255;
        const int ty = gtid >> 4, tx = gtid & 15;

        float* region = smem + kc * GROUP_F;
        float (*As)[68] = (float (*)[68])region;            // [k][m]
        float (*Bs)[64] = (float (*)[64])(region + 2176);   // [k][n]
        const float* Wm = w ? W_value : W_key;

        float acc[4][4] = {};
        const int k0 = kc * 256;

        for (int kt = k0; kt < k0 + 256; kt += 32) {
            #pragma unroll
            for (int q = 0; q < 2; ++q) {
                const int f  = gtid * 2 + q;          // 0..511
                const int ar = f >> 3;                // 0..63
                const int ac = (f & 7) << 2;          // 0..28
                float4 a = *(const float4*)(inputs + (size_t)(mt * 64 + ar) * LDA + kt + ac);
                As[ac + 0][ar] = a.x;
                As[ac + 1][ar] = a.y;
                As[ac + 2][ar] = a.z;
                As[ac + 3][ar] = a.w;
            }
            #pragma unroll
            for (int q = 0; q < 2; ++q) {
                const int f  = gtid * 2 + q;
                const int br = f >> 4;                // 0..31
                const int bc = (f & 15) << 2;         // 0..60
                *(float4*)(&Bs[br][bc]) =
                    *(const float4*)(Wm + (size_t)(kt + br) * UNITS + nt * 64 + bc);
            }
            __syncthreads();

            #pragma unroll
            for (int kk = 0; kk < 32; ++kk) {
                const float4 av = *(const float4*)(&As[kk][ty * 4]);
                const float4 bv = *(const float4*)(&Bs[kk][tx * 4]);
                acc[0][0] += av.x * bv.x; acc[0][1] += av.x * bv.y; acc[0][2] += av.x * bv.z; acc[0][3] += av.x * bv.w;
                acc[1][0] += av.y * bv.x; acc[1][1] += av.y * bv.y; acc[1][2] += av.y * bv.z; acc[1][3] += av.y * bv.w;
                acc[2][0] += av.z * bv.x; acc[2][1] += av.z * bv.y; acc[2][2] += av.z * bv.z; acc[2][3] += av.z * bv.w;
                acc[3][0] += av.w * bv.x; acc[3][1] += av.w * bv.y; acc[3][2] += av.w * bv.z; acc[3][3] += av.w * bv.w;
            }
            __syncthreads();
        }

        // each group writes its 64x64 partial over its own As/Bs region
        #pragma unroll
        for (int i = 0; i < 4; ++i) {
            float4 v = {acc[i][0], acc[i][1], acc[i][2], acc[i][3]};
            *(float4*)(region + (ty * 4 + i) * 64 + tx * 4) = v;
        }
        __syncthreads();

        // block-wide reduce of the 4 partials -> row 127 of new_M_{key,value}
        {
            const int e   = tid * 4;                  // 0..4092
            const int row = e >> 6;                   // 0..63
            const int col = e & 63;
            float4 p0 = *(const float4*)(smem + 0 * GROUP_F + e);
            float4 p1 = *(const float4*)(smem + 1 * GROUP_F + e);
            float4 p2 = *(const float4*)(smem + 2 * GROUP_F + e);
            float4 p3 = *(const float4*)(smem + 3 * GROUP_F + e);
            float4 s = {p0.x + p1.x + p2.x + p3.x,
                        p0.y + p1.y + p2.y + p3.y,
                        p0.z + p1.z + p2.z + p3.z,
                        p0.w + p1.w + p2.w + p3.w};
            *(float4*)(out + (w ? VAL_OFF : KEY_OFF)
                       + (size_t)(mt * 64 + row) * (MEM * UNITS)
                       + (size_t)(MEM - 1) * UNITS + nt * 64 + col) = s;
        }
    }
}

extern "C" void kernel_launch(void* const* d_in, const int* in_sizes, int n_in,
                              void* d_out, int out_size, void* d_ws, size_t ws_size,
                              hipStream_t stream)
{
    const float* inputs  = (const float*)d_in[0];
    const float* M_key   = (const float*)d_in[1];
    const float* M_value = (const float*)d_in[2];
    const float* W_key   = (const float*)d_in[3];
    const float* W_value = (const float*)d_in[4];
    float* out = (float*)d_out;

    hipLaunchKernelGGL(k_all, dim3(NB + NGEMM), dim3(1024), 0, stream,
                       inputs, M_key, M_value, W_key, W_value, out);
}

// Round 12
// 115.987 us; speedup vs baseline: 1.2127x; 1.0152x over previous
//
#include <hip/hip_runtime.h>

#define NB    256
#define UNITS 1024
#define EDIM  1024
#define MEM   128
#define LDA   2048   // inputs row stride (EDIM + UNITS)

// d_out layout (floats): output[256*1024] | new_M_key[256*128*1024] | new_M_value[256*128*1024]
#define KEY_OFF ((size_t)NB * UNITS)
#define VAL_OFF (KEY_OFF + (size_t)NB * MEM * UNITS)

#define NGEMM 128                 // GEMM blocks (last in grid)
#define GROUP_F 4224              // GEMM: floats per split-K group region (As 32x68 + Bs 32x64)

// fused-path LDS: buf[2][8192] (2x32KB tiles) | h 1024 | lg2 256 | at 128
#define BUF0    0
#define H_OFF   16384
#define LG2_OFF 17408
#define AT_OFF  17664
#define SMEM_FLOATS 17792         // 71168 B (>= GEMM's 4*GROUP_F = 16896 floats)

// async global->LDS DMA: 16B per lane, wave-uniform LDS base + lane*16
__device__ __forceinline__ void dma16(const float* g, float* l) {
    __builtin_amdgcn_global_load_lds((const __attribute__((address_space(1))) void*)g,
                                     (__attribute__((address_space(3))) void*)l, 16, 0, 0);
}

// counted vmcnt wait (in-order retire, m135): allow the N newest VMEM ops to
// stay outstanding; everything older is guaranteed complete.
#define WAITV(n) do { asm volatile("s_waitcnt vmcnt(" #n ")" ::: "memory"); \
                      __builtin_amdgcn_sched_barrier(0); } while (0)

// Blocks 0..255: fused attention + shift. Wave-PRIVATE pipeline (stage region
//   == consume region, r=wave>>1, hh=wave&1): no in-loop barriers. Steady-state
//   wait is vmcnt(4): the 4 newest ops are {dma(t+1) x2, stores(t-1) x2}, so
//   exactly dma(t) retires -- stores never block, prefetch stays in flight
//   (R10's vmcnt(2) mistake: it drained the stores too).
// Blocks 256..383: two 256x1024x1024 fp32 GEMMs (row 127 of new_M_*),
//   LDS-staged, in-block split-K=4 (R4 structure, proven).
__global__ __launch_bounds__(1024, 8) void k_all(
    const float* __restrict__ inputs, const float* __restrict__ M_key,
    const float* __restrict__ M_value, const float* __restrict__ W_key,
    const float* __restrict__ W_value, float* __restrict__ out)
{
    __shared__ __align__(16) float smem[SMEM_FLOATS];
    const int tid = threadIdx.x;

    if (blockIdx.x < NB) {
        // ========================= fused path =========================
        const int b    = blockIdx.x;
        const int wave = tid >> 6;
        const int lane = tid & 63;
        const int r    = wave >> 1;    // row (within 8-row tile) this wave owns
        const int hh   = wave & 1;     // column half this wave owns
        const int reg  = wave * 512;   // wave-private region inside a tile buffer

        const size_t mb = (size_t)b * (MEM * UNITS);
        const float* kbase = M_key   + mb;
        const float* vbase = M_value + mb;
        float*       kout  = out + KEY_OFF + mb;
        float*       vout  = out + VAL_OFF + mb;

        smem[H_OFF + tid] = inputs[(size_t)b * LDA + EDIM + tid];

        // prologue: stage K tile 0 (drained by the barrier below)
        dma16(kbase + reg + lane * 4,       smem + BUF0 + reg);
        dma16(kbase + reg + 256 + lane * 4, smem + BUF0 + reg + 256);
        __syncthreads();   // h ready + K(0) landed

        const float4 h0 = *(const float4*)(&smem[H_OFF + hh * 512 + lane * 4]);
        const float4 h1 = *(const float4*)(&smem[H_OFF + hh * 512 + lane * 4 + 256]);

        // per-tile stage / consume helpers (wave-private region)
        auto stageK = [&](int t) {
            const float* src = kbase + (size_t)t * 8192;
            float* lb = smem + (t & 1) * 8192;
            dma16(src + reg + lane * 4,       lb + reg);
            dma16(src + reg + 256 + lane * 4, lb + reg + 256);
        };
        auto consumeK = [&](int t) {
            const float* lbc = smem + (t & 1) * 8192 + reg;
            float4 x0 = *(const float4*)(lbc + lane * 4);
            float4 x1 = *(const float4*)(lbc + 256 + lane * 4);
            float a = x0.x*h0.x + x0.y*h0.y + x0.z*h0.z + x0.w*h0.w
                    + x1.x*h1.x + x1.y*h1.y + x1.z*h1.z + x1.w*h1.w;
            #pragma unroll
            for (int off = 32; off > 0; off >>= 1)
                a += __shfl_xor(a, off);
            const int m = t * 8 + r;
            if (lane == 0) smem[LG2_OFF + m * 2 + hh] = a;
            if (m > 0) {
                float* dst = kout + (size_t)(m - 1) * 1024 + hh * 512 + lane * 4;
                *(float4*)(dst)       = x0;
                *(float4*)(dst + 256) = x1;
            }
        };

        // ---- Phase A: K-pass, barrier-free wave-private pipeline ----
        stageK(1);
        WAITV(2);          // only dma(1) x2 outstanding -> dma(0) retired
        consumeK(0);       // issues stores(0) x2
        #pragma unroll 1
        for (int t = 1; t < 15; ++t) {
            stageK(t + 1);
            WAITV(4);      // newest 4 = dma(t+1) x2 + stores(t-1) x2 -> dma(t) done
            consumeK(t);
        }
        WAITV(2);          // newest 2 = stores(14) x2 -> dma(15) done
        consumeK(15);
        __syncthreads();   // lg2 visible to wave 0 (drains remaining stores)

        // ---- softmax over 128 logits (wave 0); all waves stage V tile 0 ----
        if (wave == 0) {
            float l0 = smem[LG2_OFF + lane * 2]        + smem[LG2_OFF + lane * 2 + 1];
            float l1 = smem[LG2_OFF + (lane + 64) * 2] + smem[LG2_OFF + (lane + 64) * 2 + 1];
            float mx = fmaxf(l0, l1);
            #pragma unroll
            for (int off = 32; off > 0; off >>= 1)
                mx = fmaxf(mx, __shfl_xor(mx, off));
            float e0 = __expf(l0 - mx), e1 = __expf(l1 - mx);
            float s = e0 + e1;
            #pragma unroll
            for (int off = 32; off > 0; off >>= 1)
                s += __shfl_xor(s, off);
            float inv = 1.0f / s;
            smem[AT_OFF + lane]      = e0 * inv;
            smem[AT_OFF + lane + 64] = e1 * inv;
        }
        dma16(vbase + reg + lane * 4,       smem + BUF0 + reg);
        dma16(vbase + reg + 256 + lane * 4, smem + BUF0 + reg + 256);
        __syncthreads();   // at ready + V(0) landed

        float4 acc0 = {0.f,0.f,0.f,0.f}, acc1 = {0.f,0.f,0.f,0.f};
        auto stageV = [&](int t) {
            const float* src = vbase + (size_t)t * 8192;
            float* lb = smem + (t & 1) * 8192;
            dma16(src + reg + lane * 4,       lb + reg);
            dma16(src + reg + 256 + lane * 4, lb + reg + 256);
        };
        auto consumeV = [&](int t) {
            const float* lbc = smem + (t & 1) * 8192 + reg;
            float4 x0 = *(const float4*)(lbc + lane * 4);
            float4 x1 = *(const float4*)(lbc + 256 + lane * 4);
            const int m = t * 8 + r;
            const float w = smem[AT_OFF + m];
            acc0.x = fmaf(w, x0.x, acc0.x); acc0.y = fmaf(w, x0.y, acc0.y);
            acc0.z = fmaf(w, x0.z, acc0.z); acc0.w = fmaf(w, x0.w, acc0.w);
            acc1.x = fmaf(w, x1.x, acc1.x); acc1.y = fmaf(w, x1.y, acc1.y);
            acc1.z = fmaf(w, x1.z, acc1.z); acc1.w = fmaf(w, x1.w, acc1.w);
            if (m > 0) {
                float* dst = vout + (size_t)(m - 1) * 1024 + hh * 512 + lane * 4;
                *(float4*)(dst)       = x0;
                *(float4*)(dst + 256) = x1;
            }
        };

        // ---- Phase C: V-pass, barrier-free wave-private pipeline ----
        stageV(1);
        WAITV(2);
        consumeV(0);
        #pragma unroll 1
        for (int t = 1; t < 15; ++t) {
            stageV(t + 1);
            WAITV(4);
            consumeV(t);
        }
        WAITV(2);
        consumeV(15);

        // per-wave output partials -> slot 0 region (wave-private)
        *(float4*)(&smem[reg + lane * 4])       = acc0;
        *(float4*)(&smem[reg + 256 + lane * 4]) = acc1;
        __syncthreads();

        // combine 8 wave-partials per column half
        {
            const int half = tid >> 9;
            const int idx  = tid & 511;
            float s = 0.f;
            #pragma unroll
            for (int j = 0; j < 8; ++j)
                s += smem[(2 * j + half) * 512 + idx];
            out[(size_t)b * UNITS + tid] = s;
        }
    } else {
        // ========================= GEMM path (R4 structure) =========================
        const int t  = blockIdx.x - NB;       // 0..127
        const int w  = t >> 6;                // which W matrix
        const int rr = t & 63;
        const int mt = rr >> 4;               // 0..3  (64 rows)
        const int nt = rr & 15;               // 0..15 (64 cols)
        const int kc   = tid >> 8;            // 0..3 (split-K group)
        const int gtid = tid & 255;
        const int ty = gtid >> 4, tx = gtid & 15;

        float* region = smem + kc * GROUP_F;
        float (*As)[68] = (float (*)[68])region;            // [k][m]
        float (*Bs)[64] = (float (*)[64])(region + 2176);   // [k][n]
        const float* Wm = w ? W_value : W_key;

        float acc[4][4] = {};
        const int k0 = kc * 256;

        for (int kt = k0; kt < k0 + 256; kt += 32) {
            #pragma unroll
            for (int q = 0; q < 2; ++q) {
                const int f  = gtid * 2 + q;          // 0..511
                const int ar = f >> 3;                // 0..63
                const int ac = (f & 7) << 2;          // 0..28
                float4 a = *(const float4*)(inputs + (size_t)(mt * 64 + ar) * LDA + kt + ac);
                As[ac + 0][ar] = a.x;
                As[ac + 1][ar] = a.y;
                As[ac + 2][ar] = a.z;
                As[ac + 3][ar] = a.w;
            }
            #pragma unroll
            for (int q = 0; q < 2; ++q) {
                const int f  = gtid * 2 + q;
                const int br = f >> 4;                // 0..31
                const int bc = (f & 15) << 2;         // 0..60
                *(float4*)(&Bs[br][bc]) =
                    *(const float4*)(Wm + (size_t)(kt + br) * UNITS + nt * 64 + bc);
            }
            __syncthreads();

            #pragma unroll
            for (int kk = 0; kk < 32; ++kk) {
                const float4 av = *(const float4*)(&As[kk][ty * 4]);
                const float4 bv = *(const float4*)(&Bs[kk][tx * 4]);
                acc[0][0] += av.x * bv.x; acc[0][1] += av.x * bv.y; acc[0][2] += av.x * bv.z; acc[0][3] += av.x * bv.w;
                acc[1][0] += av.y * bv.x; acc[1][1] += av.y * bv.y; acc[1][2] += av.y * bv.z; acc[1][3] += av.y * bv.w;
                acc[2][0] += av.z * bv.x; acc[2][1] += av.z * bv.y; acc[2][2] += av.z * bv.z; acc[2][3] += av.z * bv.w;
                acc[3][0] += av.w * bv.x; acc[3][1] += av.w * bv.y; acc[3][2] += av.w * bv.z; acc[3][3] += av.w * bv.w;
            }
            __syncthreads();
        }

        // each group writes its 64x64 partial over its own As/Bs region
        #pragma unroll
        for (int i = 0; i < 4; ++i) {
            float4 v = {acc[i][0], acc[i][1], acc[i][2], acc[i][3]};
            *(float4*)(region + (ty * 4 + i) * 64 + tx * 4) = v;
        }
        __syncthreads();

        // block-wide reduce of the 4 partials -> row 127 of new_M_{key,value}
        {
            const int e   = tid * 4;                  // 0..4092
            const int row = e >> 6;                   // 0..63
            const int col = e & 63;
            float4 p0 = *(const float4*)(smem + 0 * GROUP_F + e);
            float4 p1 = *(const float4*)(smem + 1 * GROUP_F + e);
            float4 p2 = *(const float4*)(smem + 2 * GROUP_F + e);
            float4 p3 = *(const float4*)(smem + 3 * GROUP_F + e);
            float4 s = {p0.x + p1.x + p2.x + p3.x,
                        p0.y + p1.y + p2.y + p3.y,
                        p0.z + p1.z + p2.z + p3.z,
                        p0.w + p1.w + p2.w + p3.w};
            *(float4*)(out + (w ? VAL_OFF : KEY_OFF)
                       + (size_t)(mt * 64 + row) * (MEM * UNITS)
                       + (size_t)(MEM - 1) * UNITS + nt * 64 + col) = s;
        }
    }
}

extern "C" void kernel_launch(void* const* d_in, const int* in_sizes, int n_in,
                              void* d_out, int out_size, void* d_ws, size_t ws_size,
                              hipStream_t stream)
{
    const float* inputs  = (const float*)d_in[0];
    const float* M_key   = (const float*)d_in[1];
    const float* M_value = (const float*)d_in[2];
    const float* W_key   = (const float*)d_in[3];
    const float* W_value = (const float*)d_in[4];
    float* out = (float*)d_out;

    hipLaunchKernelGGL(k_all, dim3(NB + NGEMM), dim3(1024), 0, stream,
                       inputs, M_key, M_value, W_key, W_value, out);
}

// Round 13
// 109.119 us; speedup vs baseline: 1.2890x; 1.0629x over previous
//
#include <hip/hip_runtime.h>

#define NB    256
#define UNITS 1024
#define EDIM  1024
#define MEM   128
#define LDA   2048   // inputs row stride (EDIM + UNITS)

// d_out layout (floats): output[256*1024] | new_M_key[256*128*1024] | new_M_value[256*128*1024]
#define KEY_OFF ((size_t)NB * UNITS)
#define VAL_OFF (KEY_OFF + (size_t)NB * MEM * UNITS)

#define NGEMM 128                 // GEMM blocks (last in grid)
#define GROUP_F 4224              // GEMM: floats per split-K group region (As 32x68 + Bs 32x64)

#define TILE_F 4096               // 4 rows x 1024 cols per tile (16 KB)
#define NTIL   32                 // 32 tiles = 128 rows
// fused LDS (floats): buf[3][4096] | h[1024] | lg4[512] | at[128]
#define BUF_OFF 0
#define H_OFF   12288
#define LG4_OFF 13312
#define AT_OFF  13824
#define SMEM_FLOATS (4 * GROUP_F) // 16896 floats = 67584 B (fused uses 13952)

// async global->LDS DMA: 16B per lane, wave-uniform LDS base + lane*16
__device__ __forceinline__ void dma16(const float* g, float* l) {
    __builtin_amdgcn_global_load_lds((const __attribute__((address_space(1))) void*)g,
                                     (__attribute__((address_space(3))) void*)l, 16, 0, 0);
}

// counted vmcnt wait (in-order retire, m135): keep N newest VMEM ops in flight.
#define WAITV(n) do { asm volatile("s_waitcnt vmcnt(" #n ")" ::: "memory"); \
                      __builtin_amdgcn_sched_barrier(0); } while (0)
// raw barrier (no vmcnt drain) for wave phase-alignment
#define BAR() do { asm volatile("s_barrier" ::: "memory"); \
                   __builtin_amdgcn_sched_barrier(0); } while (0)

// Blocks 0..255: fused attention + shift. Barrier-aligned counted-vmcnt pipeline
//   (AITER pattern): triple-buffered 16KB tiles, stage TWO tiles ahead; loop =
//   {vmcnt(2); s_barrier; consume(t); stage(t+2)}. vmcnt(2) retires exactly
//   dma(t) (outstanding: [s(t-2), d(t), s(t-1), d(t+1)]) -- prefetch stays in
//   flight, waves stay burst-aligned (R9 vs R12 lesson). Wave w owns region
//   [w*256, w*256+256) of every tile: stage == consume, barrier is alignment-only.
// Blocks 256..383: two 256x1024x1024 fp32 GEMMs (row 127 of new_M_*),
//   LDS-staged, in-block split-K=4 (R4 structure, proven).
__global__ __launch_bounds__(1024, 8) void k_all(
    const float* __restrict__ inputs, const float* __restrict__ M_key,
    const float* __restrict__ M_value, const float* __restrict__ W_key,
    const float* __restrict__ W_value, float* __restrict__ out)
{
    __shared__ __align__(16) float smem[SMEM_FLOATS];
    const int tid = threadIdx.x;

    if (blockIdx.x < NB) {
        // ========================= fused path =========================
        const int b    = blockIdx.x;
        const int wave = tid >> 6;
        const int lane = tid & 63;
        const int q    = wave & 3;      // column quarter (256 cols)
        const int rw   = wave >> 2;     // row within 4-row tile
        const int reg  = wave * 256;    // own region within a tile buffer

        const size_t mb = (size_t)b * (MEM * UNITS);
        const float* kbase = M_key   + mb;
        const float* vbase = M_value + mb;
        float*       kout  = out + KEY_OFF + mb;
        float*       vout  = out + VAL_OFF + mb;

        smem[H_OFF + tid] = inputs[(size_t)b * LDA + EDIM + tid];

        // prologue: stage K tiles 0,1 (drained by the barrier below)
        dma16(kbase + reg + lane * 4,          smem + BUF_OFF + reg);
        dma16(kbase + TILE_F + reg + lane * 4, smem + BUF_OFF + TILE_F + reg);
        __syncthreads();   // h ready + K(0),K(1) landed

        const float4 hq = *(const float4*)(&smem[H_OFF + q * 256 + lane * 4]);

        // ---- Phase A: K-pass ----
        #pragma unroll 1
        for (int t = 0; t < NTIL - 1; ++t) {
            WAITV(2);
            BAR();
            {   // consume tile t (own region)
                const float* lb = smem + BUF_OFF + (t % 3) * TILE_F + reg;
                float4 x = *(const float4*)(lb + lane * 4);
                float a = x.x*hq.x + x.y*hq.y + x.z*hq.z + x.w*hq.w;
                #pragma unroll
                for (int off = 32; off > 0; off >>= 1)
                    a += __shfl_xor(a, off);
                const int m = t * 4 + rw;
                if (lane == 0) smem[LG4_OFF + m * 4 + q] = a;
                if (m > 0)
                    *(float4*)(kout + (size_t)(m - 1) * 1024 + q * 256 + lane * 4) = x;
            }
            if (t + 2 < NTIL)
                dma16(kbase + (size_t)(t + 2) * TILE_F + reg + lane * 4,
                      smem + BUF_OFF + ((t + 2) % 3) * TILE_F + reg);
        }
        // epilogue tile 31: outstanding [s29, d31, s30] -> vmcnt(1) retires d31
        WAITV(1);
        BAR();
        {
            const int t = NTIL - 1;
            const float* lb = smem + BUF_OFF + (t % 3) * TILE_F + reg;
            float4 x = *(const float4*)(lb + lane * 4);
            float a = x.x*hq.x + x.y*hq.y + x.z*hq.z + x.w*hq.w;
            #pragma unroll
            for (int off = 32; off > 0; off >>= 1)
                a += __shfl_xor(a, off);
            const int m = t * 4 + rw;
            if (lane == 0) smem[LG4_OFF + m * 4 + q] = a;
            *(float4*)(kout + (size_t)(m - 1) * 1024 + q * 256 + lane * 4) = x;
        }
        __syncthreads();   // lg4 visible; stores drained

        // stage V tiles 0,1; softmax on wave 0 meanwhile
        dma16(vbase + reg + lane * 4,          smem + BUF_OFF + reg);
        dma16(vbase + TILE_F + reg + lane * 4, smem + BUF_OFF + TILE_F + reg);
        if (wave == 0) {
            float4 g0 = *(const float4*)(&smem[LG4_OFF + lane * 4]);
            float4 g1 = *(const float4*)(&smem[LG4_OFF + (lane + 64) * 4]);
            float l0 = g0.x + g0.y + g0.z + g0.w;
            float l1 = g1.x + g1.y + g1.z + g1.w;
            float mx = fmaxf(l0, l1);
            #pragma unroll
            for (int off = 32; off > 0; off >>= 1)
                mx = fmaxf(mx, __shfl_xor(mx, off));
            float e0 = __expf(l0 - mx), e1 = __expf(l1 - mx);
            float s = e0 + e1;
            #pragma unroll
            for (int off = 32; off > 0; off >>= 1)
                s += __shfl_xor(s, off);
            float inv = 1.0f / s;
            smem[AT_OFF + lane]      = e0 * inv;
            smem[AT_OFF + lane + 64] = e1 * inv;
        }
        __syncthreads();   // at ready + V(0),V(1) landed

        // ---- Phase C: V-pass ----
        float4 acc = {0.f, 0.f, 0.f, 0.f};
        #pragma unroll 1
        for (int t = 0; t < NTIL - 1; ++t) {
            WAITV(2);
            BAR();
            {
                const float* lb = smem + BUF_OFF + (t % 3) * TILE_F + reg;
                float4 x = *(const float4*)(lb + lane * 4);
                const int m = t * 4 + rw;
                const float w = smem[AT_OFF + m];
                acc.x = fmaf(w, x.x, acc.x); acc.y = fmaf(w, x.y, acc.y);
                acc.z = fmaf(w, x.z, acc.z); acc.w = fmaf(w, x.w, acc.w);
                if (m > 0)
                    *(float4*)(vout + (size_t)(m - 1) * 1024 + q * 256 + lane * 4) = x;
            }
            if (t + 2 < NTIL)
                dma16(vbase + (size_t)(t + 2) * TILE_F + reg + lane * 4,
                      smem + BUF_OFF + ((t + 2) % 3) * TILE_F + reg);
        }
        WAITV(1);
        BAR();
        {
            const int t = NTIL - 1;
            const float* lb = smem + BUF_OFF + (t % 3) * TILE_F + reg;
            float4 x = *(const float4*)(lb + lane * 4);
            const int m = t * 4 + rw;
            const float w = smem[AT_OFF + m];
            acc.x = fmaf(w, x.x, acc.x); acc.y = fmaf(w, x.y, acc.y);
            acc.z = fmaf(w, x.z, acc.z); acc.w = fmaf(w, x.w, acc.w);
            *(float4*)(vout + (size_t)(m - 1) * 1024 + q * 256 + lane * 4) = x;
        }
        __syncthreads();   // all dma/stores drained

        // per-wave output partials (cols q*256..q*256+255) -> buf[0] region
        *(float4*)(&smem[BUF_OFF + wave * 256 + lane * 4]) = acc;
        __syncthreads();

        // combine: out col c = tid; quarter qq = c>>8, idx = c&255;
        // contributing waves {qq, qq+4, qq+8, qq+12}
        {
            const int qq  = tid >> 8;
            const int idx = tid & 255;
            float s = smem[BUF_OFF + (qq + 0)  * 256 + idx]
                    + smem[BUF_OFF + (qq + 4)  * 256 + idx]
                    + smem[BUF_OFF + (qq + 8)  * 256 + idx]
                    + smem[BUF_OFF + (qq + 12) * 256 + idx];
            out[(size_t)b * UNITS + tid] = s;
        }
    } else {
        // ========================= GEMM path (R4 structure) =========================
        const int t  = blockIdx.x - NB;       // 0..127
        const int w  = t >> 6;                // which W matrix
        const int rr = t & 63;
        const int mt = rr >> 4;               // 0..3  (64 rows)
        const int nt = rr & 15;               // 0..15 (64 cols)
        const int kc   = tid >> 8;            // 0..3 (split-K group)
        const int gtid = tid & 255;
        const int ty = gtid >> 4, tx = gtid & 15;

        float* region = smem + kc * GROUP_F;
        float (*As)[68] = (float (*)[68])region;            // [k][m]
        float (*Bs)[64] = (float (*)[64])(region + 2176);   // [k][n]
        const float* Wm = w ? W_value : W_key;

        float acc[4][4] = {};
        const int k0 = kc * 256;

        for (int kt = k0; kt < k0 + 256; kt += 32) {
            #pragma unroll
            for (int qq = 0; qq < 2; ++qq) {
                const int f  = gtid * 2 + qq;         // 0..511
                const int ar = f >> 3;                // 0..63
                const int ac = (f & 7) << 2;          // 0..28
                float4 a = *(const float4*)(inputs + (size_t)(mt * 64 + ar) * LDA + kt + ac);
                As[ac + 0][ar] = a.x;
                As[ac + 1][ar] = a.y;
                As[ac + 2][ar] = a.z;
                As[ac + 3][ar] = a.w;
            }
            #pragma unroll
            for (int qq = 0; qq < 2; ++qq) {
                const int f  = gtid * 2 + qq;
                const int br = f >> 4;                // 0..31
                const int bc = (f & 15) << 2;         // 0..60
                *(float4*)(&Bs[br][bc]) =
                    *(const float4*)(Wm + (size_t)(kt + br) * UNITS + nt * 64 + bc);
            }
            __syncthreads();

            #pragma unroll
            for (int kk = 0; kk < 32; ++kk) {
                const float4 av = *(const float4*)(&As[kk][ty * 4]);
                const float4 bv = *(const float4*)(&Bs[kk][tx * 4]);
                acc[0][0] += av.x * bv.x; acc[0][1] += av.x * bv.y; acc[0][2] += av.x * bv.z; acc[0][3] += av.x * bv.w;
                acc[1][0] += av.y * bv.x; acc[1][1] += av.y * bv.y; acc[1][2] += av.y * bv.z; acc[1][3] += av.y * bv.w;
                acc[2][0] += av.z * bv.x; acc[2][1] += av.z * bv.y; acc[2][2] += av.z * bv.z; acc[2][3] += av.z * bv.w;
                acc[3][0] += av.w * bv.x; acc[3][1] += av.w * bv.y; acc[3][2] += av.w * bv.z; acc[3][3] += av.w * bv.w;
            }
            __syncthreads();
        }

        // each group writes its 64x64 partial over its own As/Bs region
        #pragma unroll
        for (int i = 0; i < 4; ++i) {
            float4 v = {acc[i][0], acc[i][1], acc[i][2], acc[i][3]};
            *(float4*)(region + (ty * 4 + i) * 64 + tx * 4) = v;
        }
        __syncthreads();

        // block-wide reduce of the 4 partials -> row 127 of new_M_{key,value}
        {
            const int e   = tid * 4;                  // 0..4092
            const int row = e >> 6;                   // 0..63
            const int col = e & 63;
            float4 p0 = *(const float4*)(smem + 0 * GROUP_F + e);
            float4 p1 = *(const float4*)(smem + 1 * GROUP_F + e);
            float4 p2 = *(const float4*)(smem + 2 * GROUP_F + e);
            float4 p3 = *(const float4*)(smem + 3 * GROUP_F + e);
            float4 s = {p0.x + p1.x + p2.x + p3.x,
                        p0.y + p1.y + p2.y + p3.y,
                        p0.z + p1.z + p2.z + p3.z,
                        p0.w + p1.w + p2.w + p3.w};
            *(float4*)(out + (w ? VAL_OFF : KEY_OFF)
                       + (size_t)(mt * 64 + row) * (MEM * UNITS)
                       + (size_t)(MEM - 1) * UNITS + nt * 64 + col) = s;
        }
    }
}

extern "C" void kernel_launch(void* const* d_in, const int* in_sizes, int n_in,
                              void* d_out, int out_size, void* d_ws, size_t ws_size,
                              hipStream_t stream)
{
    const float* inputs  = (const float*)d_in[0];
    const float* M_key   = (const float*)d_in[1];
    const float* M_value = (const float*)d_in[2];
    const float* W_key   = (const float*)d_in[3];
    const float* W_value = (const float*)d_in[4];
    float* out = (float*)d_out;

    hipLaunchKernelGGL(k_all, dim3(NB + NGEMM), dim3(1024), 0, stream,
                       inputs, M_key, M_value, W_key, W_value, out);
}